// Round 2
// baseline (167.491 us; speedup 1.0000x reference)
//
#include <hip/hip_runtime.h>

#define B 4
#define TE 512
#define TD 256
#define D 256

#define C2    2.8853900817779268f   // 2/ln(2): exp(2x) = exp2(C2*x)
#define LOG2E 1.4426950408889634f

// 4-way division combine: q += sum_i v_i / p_i with ONE rcp.
// p products bounded by (e^13)^4 ~ 3e22 << FLT_MAX for these inputs.
__device__ __forceinline__ void qcomb4(float& q, const float4& v,
                                       float p0, float p1, float p2, float p3)
{
    const float n01 = fmaf(v.y, p0, v.x * p1);
    const float d01 = p0 * p1;
    const float n23 = fmaf(v.w, p2, v.z * p3);
    const float d23 = p2 * p3;
    const float num = fmaf(n23, d01, n01 * d23);
    const float den = d01 * d23;
    q = fmaf(num, __builtin_amdgcn_rcpf(den), q);
}

__device__ __forceinline__ void score4(float& q, const float4& v4,
                                       const float4& w, const float4& a)
{
    qcomb4(q, v4, fmaf(w.x, a.x, 1.0f), fmaf(w.y, a.y, 1.0f),
                  fmaf(w.z, a.z, 1.0f), fmaf(w.w, a.w, 1.0f));
}

// ---------------------------------------------------------------------------
// K1: BOTH projections in one balanced launch.
// 256 blocks x 512 threads = 1 block/CU (no tail), 2 waves/SIMD.
// Block (b, j): enc rows e0=8j..8j+7 -> ewt (float4-d layout) AND
//               dec rows t0=4j..4j+3 -> eu.
// Thread (d = tid&255, h = tid>>8): half h handles enc rows 4h..4h+3 and
// dec rows 2h..2h+1. Both halves read the same W/Ua columns in lockstep
// (L1 broadcast) -> block weight traffic stays 512 KB.
// XCD-affine: xcd = blk&7 -> b = xcd>>1, so each XCD's L2 only sees its b.
// ewt layout: ewt4[b][dd][e] = float4 over d = 4dd..4dd+3 (score loads
// become lane-coalesced dwordx4).
// ---------------------------------------------------------------------------
__global__ __launch_bounds__(512) void proj_kernel(
    const float* __restrict__ enc, const float* __restrict__ dec,
    const float* __restrict__ Wa,  const float* __restrict__ Ua,
    float* __restrict__ ewt, float* __restrict__ eu)
{
    __shared__ float a_lds[8 * 256];   // 8 enc rows
    __shared__ float d_lds[4 * 256];   // 4 dec rows

    const int tid = threadIdx.x;
    const int blk = blockIdx.x;
    const int xcd = blk & 7;
    const int b   = xcd >> 1;
    const int j   = ((xcd & 1) << 5) | (blk >> 3);   // 0..63
    const int e0  = j * 8;
    const int t0  = j * 4;

    {
        const float4* esrc = (const float4*)(enc + ((size_t)(b * 512 + e0)) * 256);
        ((float4*)a_lds)[tid] = esrc[tid];
        if (tid < 256) {
            const float4* dsrc = (const float4*)(dec + ((size_t)(b * 256 + t0)) * 256);
            ((float4*)d_lds)[tid] = dsrc[tid];
        }
    }
    __syncthreads();

    const int d = tid & 255;
    const int h = tid >> 8;
    const float* __restrict__ arow = a_lds + (4 * h) * 256;
    const float* __restrict__ drow = d_lds + (2 * h) * 256;

    float acc[4]  = {0.f, 0.f, 0.f, 0.f};
    float dacc[2] = {0.f, 0.f};

    #pragma unroll 4
    for (int k = 0; k < 256; k += 4) {
        const float w0 = Wa[(k + 0) * 256 + d];
        const float w1 = Wa[(k + 1) * 256 + d];
        const float w2 = Wa[(k + 2) * 256 + d];
        const float w3 = Wa[(k + 3) * 256 + d];
        const float u0 = Ua[(k + 0) * 256 + d];
        const float u1 = Ua[(k + 1) * 256 + d];
        const float u2 = Ua[(k + 2) * 256 + d];
        const float u3 = Ua[(k + 3) * 256 + d];
        #pragma unroll
        for (int r = 0; r < 4; r++) {
            const float4 a4 = *(const float4*)&arow[r * 256 + k];
            acc[r] = fmaf(a4.x, w0, acc[r]);
            acc[r] = fmaf(a4.y, w1, acc[r]);
            acc[r] = fmaf(a4.z, w2, acc[r]);
            acc[r] = fmaf(a4.w, w3, acc[r]);
        }
        #pragma unroll
        for (int r = 0; r < 2; r++) {
            const float4 d4 = *(const float4*)&drow[r * 256 + k];
            dacc[r] = fmaf(d4.x, u0, dacc[r]);
            dacc[r] = fmaf(d4.y, u1, dacc[r]);
            dacc[r] = fmaf(d4.z, u2, dacc[r]);
            dacc[r] = fmaf(d4.w, u3, dacc[r]);
        }
    }

    // enc rows 4h..4h+3 -> ewt float4-component store
    {
        float* o = ewt + (((size_t)(b * 64 + (d >> 2)) * 512 + e0 + 4 * h) << 2)
                       + (d & 3);
        #pragma unroll
        for (int r = 0; r < 4; r++)
            o[r * 4] = __builtin_amdgcn_exp2f(acc[r] * C2);
    }
    // dec rows 2h..2h+1 -> eu, coalesced dword stores
    {
        #pragma unroll
        for (int r = 0; r < 2; r++)
            eu[(size_t)(b * 256 + t0 + 2 * h + r) * 256 + d] =
                __builtin_amdgcn_exp2f(dacc[r] * C2);
    }
}

// ---------------------------------------------------------------------------
// K2: fused score + softmax + context. One block per (b, t-quad):
// 256 blocks x 1024 threads, b-affine XCD mapping (same as K1).
// Score: e = tid&511 serves ALL 4 t's over a d-half (tp = tid>>9); partials
//   combined via LDS. ewt loads: 32 dwordx4/thread (8x fewer VMEM instrs
//   than the scalar-dword variant, same L2 bytes).
// Softmax / context: unchanged from the 106 us build.
// ---------------------------------------------------------------------------
__global__ __launch_bounds__(1024) void attn_kernel(
    const float* __restrict__ enc, const float* __restrict__ ewt,
    const float* __restrict__ eu,  const float* __restrict__ Va,
    float* __restrict__ ctx, float* __restrict__ aw)
{
    __shared__ float eul[4 * 256];      // 4 Eu rows
    __shared__ float val[256];          // Va
    __shared__ float sc[4][TE];         // scores -> weights (8 KB)
    __shared__ float wred[2][4][4];     // softmax cross-wave combine
    __shared__ float part[4][4][256];   // scratch: score halves / ctx partials

    const int tid = threadIdx.x;
    const int blk = blockIdx.x;
    const int xcd = blk & 7;
    const int b   = xcd >> 1;                         // 2 XCDs per batch
    const int tq  = ((xcd & 1) << 5) | (blk >> 3);    // 0..63 t-quad
    const int t0  = tq * 4;
    const int bt0 = b * 256 + t0;

    float* const scratch = &part[0][0][0];            // 4096 floats

    if (tid < 256) val[tid] = Va[tid];
    eul[tid] = eu[(size_t)bt0 * 256 + tid];
    __syncthreads();

    // ---- scores: score'[t][e] = -2 * sum_d v_d / (1 + Ew*Eu) ------------
    {
        const int e  = tid & 511;
        const int tp = tid >> 9;           // d-half: d in [128*tp, 128*tp+128)
        const float4* __restrict__ ewb =
            (const float4*)ewt + (size_t)(b * 64 + tp * 32) * 512 + e;
        float q0 = 0.f, q1 = 0.f, q2 = 0.f, q3 = 0.f;

        #pragma unroll 2
        for (int it = 0; it < 16; ++it) {
            const float4 w0 = ewb[(it * 2 + 0) * 512];   // d-quad 2it
            const float4 w1 = ewb[(it * 2 + 1) * 512];   // d-quad 2it+1
            const int d0 = (tp * 32 + it * 2) * 4;
            {
                const float4 v4 = *(const float4*)&val[d0];
                score4(q0, v4, w0, *(const float4*)&eul[      d0]);
                score4(q1, v4, w0, *(const float4*)&eul[256 + d0]);
                score4(q2, v4, w0, *(const float4*)&eul[512 + d0]);
                score4(q3, v4, w0, *(const float4*)&eul[768 + d0]);
            }
            {
                const int d1 = d0 + 4;
                const float4 v4 = *(const float4*)&val[d1];
                score4(q0, v4, w1, *(const float4*)&eul[      d1]);
                score4(q1, v4, w1, *(const float4*)&eul[256 + d1]);
                score4(q2, v4, w1, *(const float4*)&eul[512 + d1]);
                score4(q3, v4, w1, *(const float4*)&eul[768 + d1]);
            }
        }

        if (tp) {
            scratch[       e] = q0;
            scratch[512  + e] = q1;
            scratch[1024 + e] = q2;
            scratch[1536 + e] = q3;
        }
        __syncthreads();
        if (!tp) {
            sc[0][e] = -2.0f * (q0 + scratch[       e]);
            sc[1][e] = -2.0f * (q1 + scratch[512  + e]);
            sc[2][e] = -2.0f * (q2 + scratch[1024 + e]);
            sc[3][e] = -2.0f * (q3 + scratch[1536 + e]);
        }
    }
    __syncthreads();

    // ---- softmax: wave wv -> (t = wv>>2, seg = wv&3) ---------------------
    {
        const int wv   = tid >> 6;
        const int lane = tid & 63;
        const int t    = wv >> 2;
        const int seg  = wv & 3;
        float* __restrict__ srow = &sc[t][seg * 128];

        const float x0 = srow[lane];
        const float x1 = srow[lane + 64];

        float m = fmaxf(x0, x1);
        #pragma unroll
        for (int s = 32; s > 0; s >>= 1) m = fmaxf(m, __shfl_xor(m, s, 64));
        if (lane == 0) wred[0][t][seg] = m;
        __syncthreads();
        const float4 mm = *(const float4*)&wred[0][t][0];
        const float M = fmaxf(fmaxf(mm.x, mm.y), fmaxf(mm.z, mm.w));

        const float g0 = __builtin_amdgcn_exp2f((x0 - M) * LOG2E);
        const float g1 = __builtin_amdgcn_exp2f((x1 - M) * LOG2E);

        float ssum = g0 + g1;
        #pragma unroll
        for (int s = 32; s > 0; s >>= 1) ssum += __shfl_xor(ssum, s, 64);
        if (lane == 0) wred[1][t][seg] = ssum;
        __syncthreads();
        const float4 sm = *(const float4*)&wred[1][t][0];
        const float inv = __builtin_amdgcn_rcpf((sm.x + sm.y) + (sm.z + sm.w));

        const float p0 = g0 * inv, p1 = g1 * inv;
        srow[lane]      = p0;
        srow[lane + 64] = p1;
        float* __restrict__ ao = aw + ((size_t)(bt0 + t)) * 512 + seg * 128;
        ao[lane]      = p0;
        ao[lane + 64] = p1;
    }
    __syncthreads();

    // ---- context: eg = tid>>8 (128 e's each), dl = tid&255 ---------------
    {
        const int eg = tid >> 8;
        const int dl = tid & 255;
        const float* __restrict__ eb =
            enc + ((size_t)b * 512 + eg * 128) * 256 + dl;
        const int e0 = eg * 128;

        float c0 = 0.f, c1 = 0.f, c2 = 0.f, c3 = 0.f;
        #pragma unroll 4
        for (int jj = 0; jj < 128; jj += 4) {
            const float4 w0 = *(const float4*)&sc[0][e0 + jj];
            const float4 w1 = *(const float4*)&sc[1][e0 + jj];
            const float4 w2 = *(const float4*)&sc[2][e0 + jj];
            const float4 w3 = *(const float4*)&sc[3][e0 + jj];
            const float r0 = eb[(jj + 0) * 256];
            const float r1 = eb[(jj + 1) * 256];
            const float r2 = eb[(jj + 2) * 256];
            const float r3 = eb[(jj + 3) * 256];
            c0 = fmaf(w0.x, r0, c0); c0 = fmaf(w0.y, r1, c0); c0 = fmaf(w0.z, r2, c0); c0 = fmaf(w0.w, r3, c0);
            c1 = fmaf(w1.x, r0, c1); c1 = fmaf(w1.y, r1, c1); c1 = fmaf(w1.z, r2, c1); c1 = fmaf(w1.w, r3, c1);
            c2 = fmaf(w2.x, r0, c2); c2 = fmaf(w2.y, r1, c2); c2 = fmaf(w2.z, r2, c2); c2 = fmaf(w2.w, r3, c2);
            c3 = fmaf(w3.x, r0, c3); c3 = fmaf(w3.y, r1, c3); c3 = fmaf(w3.z, r2, c3); c3 = fmaf(w3.w, r3, c3);
        }
        part[eg][0][dl] = c0;
        part[eg][1][dl] = c1;
        part[eg][2][dl] = c2;
        part[eg][3][dl] = c3;
    }
    __syncthreads();

    {
        const int t  = tid >> 8;       // 0..3
        const int dl = tid & 255;
        ctx[((size_t)(bt0 + t)) * 256 + dl] =
            (part[0][t][dl] + part[1][t][dl]) +
            (part[2][t][dl] + part[3][t][dl]);
    }
}

extern "C" void kernel_launch(void* const* d_in, const int* in_sizes, int n_in,
                              void* d_out, int out_size, void* d_ws, size_t ws_size,
                              hipStream_t stream) {
    const float* enc = (const float*)d_in[0];   // [4,512,256]
    const float* dec = (const float*)d_in[1];   // [4,256,256]
    const float* Wa  = (const float*)d_in[2];   // [256,256]
    const float* Ua  = (const float*)d_in[3];   // [256,256]
    const float* Va  = (const float*)d_in[4];   // [256,1]

    float* out = (float*)d_out;
    float* ctx = out;                           // [4,256,256]
    float* aw  = out + B * TD * D;              // [4,256,512]

    float* ewt = (float*)d_ws;                  // [4][64 dd][512 e] float4, 2 MB
    float* eu  = ewt + (size_t)B * D * TE;      // [4][256 t][256 d], 1 MB

    proj_kernel<<<dim3(256), dim3(512),  0, stream>>>(enc, dec, Wa, Ua, ewt, eu);
    attn_kernel<<<dim3(256), dim3(1024), 0, stream>>>(enc, ewt, eu, Va, ctx, aw);
}

// Round 3
// 105.887 us; speedup vs baseline: 1.5818x; 1.5818x over previous
//
#include <hip/hip_runtime.h>

#define B 4
#define TE 512
#define TD 256
#define D 256

#define C2    2.8853900817779268f   // 2/ln(2): exp(2x) = exp2(C2*x)
#define LOG2E 1.4426950408889634f

// ---------------------------------------------------------------------------
// K1: projections + exp2 — exact round-0 structure (proven 106 µs build),
// plus b-affine XCD swizzle (pure index remap, zero instruction cost).
//   ewt[b][d][e] = exp2(C2 * (enc@W_a)[b][e][d])   (TRANSPOSED, e contiguous)
//   eu [b][t][d] = exp2(C2 * (dec@U_a)[b][t][d])
// enc blocks 0..255: xcd = blk&7 -> b = xcd>>1; dec blocks 256..383 likewise
// (256 % 8 == 0, so dispatch-order XCD assignment is preserved).
// ---------------------------------------------------------------------------
__global__ __launch_bounds__(256) void proj_kernel(
    const float* __restrict__ enc, const float* __restrict__ dec,
    const float* __restrict__ Wa,  const float* __restrict__ Ua,
    float* __restrict__ ewt, float* __restrict__ eu)
{
    __shared__ float a_lds[8 * 256];
    const int tid = threadIdx.x;
    const int blk = blockIdx.x;
    const bool is_enc = blk < 256;
    const float* __restrict__ A = is_enc ? enc : dec;
    const float* __restrict__ W = is_enc ? Wa  : Ua;

    int row0;
    if (is_enc) {
        const int xcd = blk & 7;
        const int b   = xcd >> 1;
        const int j   = ((xcd & 1) << 5) | (blk >> 3);     // 0..63
        row0 = b * 512 + j * 8;                            // flattened enc row
    } else {
        const int blk2 = blk - 256;                        // 0..127
        const int xcd  = blk2 & 7;
        const int b    = xcd >> 1;
        const int j    = ((xcd & 1) << 4) | (blk2 >> 3);   // 0..31
        row0 = b * 256 + j * 8;                            // flattened dec row
    }

    {
        const float4* src = (const float4*)(A + (size_t)row0 * 256);
        ((float4*)a_lds)[tid]       = src[tid];
        ((float4*)a_lds)[tid + 256] = src[tid + 256];
    }
    __syncthreads();

    float acc[8] = {0.f,0.f,0.f,0.f,0.f,0.f,0.f,0.f};

    #pragma unroll 4
    for (int k = 0; k < 256; k += 4) {
        const float w0 = W[(k + 0) * 256 + tid];
        const float w1 = W[(k + 1) * 256 + tid];
        const float w2 = W[(k + 2) * 256 + tid];
        const float w3 = W[(k + 3) * 256 + tid];
        #pragma unroll
        for (int r = 0; r < 8; r++) {
            const float4 a4 = *(const float4*)&a_lds[r * 256 + k];
            acc[r] = fmaf(a4.x, w0, acc[r]);
            acc[r] = fmaf(a4.y, w1, acc[r]);
            acc[r] = fmaf(a4.z, w2, acc[r]);
            acc[r] = fmaf(a4.w, w3, acc[r]);
        }
    }

    float f[8];
    #pragma unroll
    for (int r = 0; r < 8; r++)
        f[r] = __builtin_amdgcn_exp2f(acc[r] * C2);

    if (is_enc) {
        const int b  = row0 >> 9;
        const int e0 = row0 & 511;
        float* o = ewt + ((size_t)(b * 256 + tid)) * 512 + e0;   // e-contig
        *(float4*)(o + 0) = make_float4(f[0], f[1], f[2], f[3]);
        *(float4*)(o + 4) = make_float4(f[4], f[5], f[6], f[7]);
    } else {
        #pragma unroll
        for (int r = 0; r < 8; r++)
            eu[(size_t)(row0 + r) * 256 + tid] = f[r];
    }
}

// 4-way division combine: returns q += sum_i v_i / p_i  with ONE rcp.
__device__ __forceinline__ void qcomb4(float& q, const float4& v,
                                       float p0, float p1, float p2, float p3)
{
    const float n01 = fmaf(v.y, p0, v.x * p1);
    const float d01 = p0 * p1;
    const float n23 = fmaf(v.w, p2, v.z * p3);
    const float d23 = p2 * p3;
    const float num = fmaf(n23, d01, n01 * d23);
    const float den = d01 * d23;
    q = fmaf(num, __builtin_amdgcn_rcpf(den), q);
}

// ---------------------------------------------------------------------------
// K2: fused score + softmax + context — exact round-0 structure, plus the
// same b-affine XCD swizzle (per-XCD hot set 1.3 MB -> fully L2-resident).
// 256 blocks x 1024 threads = 16 waves/CU = 4 waves/SIMD.
// ---------------------------------------------------------------------------
__global__ __launch_bounds__(1024) void attn_kernel(
    const float* __restrict__ enc, const float* __restrict__ ewt,
    const float* __restrict__ eu,  const float* __restrict__ Va,
    float* __restrict__ ctx, float* __restrict__ aw)
{
    __shared__ float eul[4 * 256];      // 4 Eu rows
    __shared__ float val[256];          // Va
    __shared__ float sc[4][TE];         // scores -> weights (8 KB)
    __shared__ float wred[2][4][4];     // [phase][t][seg]
    __shared__ float part[4][4][256];   // [e-group][t][d] (16 KB)

    const int tid = threadIdx.x;
    const int blk = blockIdx.x;
    const int xcd = blk & 7;
    const int b   = xcd >> 1;                         // 2 XCDs per batch
    const int tq  = ((xcd & 1) << 5) | (blk >> 3);    // 0..63 t-quad
    const int t0  = tq * 4;
    const int bt0 = b * 256 + t0;

    if (tid < 256) val[tid] = Va[tid];
    eul[tid] = eu[(size_t)bt0 * 256 + tid];
    __syncthreads();

    // ---- scores ---------------------------------------------------------
    {
        const int e  = tid & 511;
        const int tp = tid >> 9;                  // 0..1 -> t-pair
        const float* __restrict__ ewb = ewt + (size_t)b * 256 * 512 + e;
        const float* __restrict__ ea0 = &eul[(2 * tp + 0) * 256];
        const float* __restrict__ ea1 = &eul[(2 * tp + 1) * 256];

        float q0 = 0.f, q1 = 0.f;

        for (int d = 0; d < 256; d += 8) {
            float w[8];
            #pragma unroll
            for (int j = 0; j < 8; j++) w[j] = ewb[(d + j) * 512];

            #pragma unroll
            for (int h = 0; h < 2; h++) {
                const int dd = d + h * 4;
                const float4 v4 = *(const float4*)&val[dd];
                const float4 a0 = *(const float4*)&ea0[dd];
                const float4 a1 = *(const float4*)&ea1[dd];
                const float* wj = &w[h * 4];

                qcomb4(q0, v4,
                       fmaf(wj[0], a0.x, 1.0f), fmaf(wj[1], a0.y, 1.0f),
                       fmaf(wj[2], a0.z, 1.0f), fmaf(wj[3], a0.w, 1.0f));
                qcomb4(q1, v4,
                       fmaf(wj[0], a1.x, 1.0f), fmaf(wj[1], a1.y, 1.0f),
                       fmaf(wj[2], a1.z, 1.0f), fmaf(wj[3], a1.w, 1.0f));
            }
        }
        sc[2 * tp + 0][e] = -2.0f * q0;
        sc[2 * tp + 1][e] = -2.0f * q1;
    }
    __syncthreads();

    // ---- softmax: wave wv -> (t = wv>>2, seg = wv&3) --------------------
    {
        const int wv   = tid >> 6;
        const int lane = tid & 63;
        const int t    = wv >> 2;
        const int seg  = wv & 3;
        float* __restrict__ srow = &sc[t][seg * 128];

        const float x0 = srow[lane];
        const float x1 = srow[lane + 64];

        float m = fmaxf(x0, x1);
        #pragma unroll
        for (int s = 32; s > 0; s >>= 1) m = fmaxf(m, __shfl_xor(m, s, 64));
        if (lane == 0) wred[0][t][seg] = m;
        __syncthreads();
        const float4 mm = *(const float4*)&wred[0][t][0];
        const float M = fmaxf(fmaxf(mm.x, mm.y), fmaxf(mm.z, mm.w));

        const float g0 = __builtin_amdgcn_exp2f((x0 - M) * LOG2E);
        const float g1 = __builtin_amdgcn_exp2f((x1 - M) * LOG2E);

        float ssum = g0 + g1;
        #pragma unroll
        for (int s = 32; s > 0; s >>= 1) ssum += __shfl_xor(ssum, s, 64);
        if (lane == 0) wred[1][t][seg] = ssum;
        __syncthreads();
        const float4 sm = *(const float4*)&wred[1][t][0];
        const float inv = __builtin_amdgcn_rcpf((sm.x + sm.y) + (sm.z + sm.w));

        const float p0 = g0 * inv, p1 = g1 * inv;
        srow[lane]      = p0;
        srow[lane + 64] = p1;
        float* __restrict__ ao = aw + ((size_t)(bt0 + t)) * 512 + seg * 128;
        ao[lane]      = p0;
        ao[lane + 64] = p1;
    }
    __syncthreads();

    // ---- context: eg = tid>>8 (128 e's each), dl = tid&255 --------------
    {
        const int eg = tid >> 8;
        const int dl = tid & 255;
        const float* __restrict__ eb =
            enc + ((size_t)b * 512 + eg * 128) * 256 + dl;
        const int e0 = eg * 128;

        float c0 = 0.f, c1 = 0.f, c2 = 0.f, c3 = 0.f;
        #pragma unroll 4
        for (int j = 0; j < 128; j += 4) {
            const float4 w0 = *(const float4*)&sc[0][e0 + j];
            const float4 w1 = *(const float4*)&sc[1][e0 + j];
            const float4 w2 = *(const float4*)&sc[2][e0 + j];
            const float4 w3 = *(const float4*)&sc[3][e0 + j];
            const float r0 = eb[(j + 0) * 256];
            const float r1 = eb[(j + 1) * 256];
            const float r2 = eb[(j + 2) * 256];
            const float r3 = eb[(j + 3) * 256];
            c0 = fmaf(w0.x, r0, c0); c0 = fmaf(w0.y, r1, c0); c0 = fmaf(w0.z, r2, c0); c0 = fmaf(w0.w, r3, c0);
            c1 = fmaf(w1.x, r0, c1); c1 = fmaf(w1.y, r1, c1); c1 = fmaf(w1.z, r2, c1); c1 = fmaf(w1.w, r3, c1);
            c2 = fmaf(w2.x, r0, c2); c2 = fmaf(w2.y, r1, c2); c2 = fmaf(w2.z, r2, c2); c2 = fmaf(w2.w, r3, c2);
            c3 = fmaf(w3.x, r0, c3); c3 = fmaf(w3.y, r1, c3); c3 = fmaf(w3.z, r2, c3); c3 = fmaf(w3.w, r3, c3);
        }
        part[eg][0][dl] = c0;
        part[eg][1][dl] = c1;
        part[eg][2][dl] = c2;
        part[eg][3][dl] = c3;
    }
    __syncthreads();

    {
        const int t  = tid >> 8;       // 0..3
        const int dl = tid & 255;
        ctx[((size_t)(bt0 + t)) * 256 + dl] =
            (part[0][t][dl] + part[1][t][dl]) +
            (part[2][t][dl] + part[3][t][dl]);
    }
}

extern "C" void kernel_launch(void* const* d_in, const int* in_sizes, int n_in,
                              void* d_out, int out_size, void* d_ws, size_t ws_size,
                              hipStream_t stream) {
    const float* enc = (const float*)d_in[0];   // [4,512,256]
    const float* dec = (const float*)d_in[1];   // [4,256,256]
    const float* Wa  = (const float*)d_in[2];   // [256,256]
    const float* Ua  = (const float*)d_in[3];   // [256,256]
    const float* Va  = (const float*)d_in[4];   // [256,1]

    float* out = (float*)d_out;
    float* ctx = out;                           // [4,256,256]
    float* aw  = out + B * TD * D;              // [4,256,512]

    float* ewt = (float*)d_ws;                  // [4][256 d][512 e]  2 MB
    float* eu  = ewt + (size_t)B * D * TE;      // [4][256 t][256 d]  1 MB

    proj_kernel<<<dim3(384), dim3(256), 0, stream>>>(enc, dec, Wa, Ua, ewt, eu);
    attn_kernel<<<dim3(256), dim3(1024), 0, stream>>>(enc, ewt, eu, Va, ctx, aw);
}

// Round 4
// 105.648 us; speedup vs baseline: 1.5854x; 1.0023x over previous
//
#include <hip/hip_runtime.h>

#define B 4
#define TE 512
#define TD 256
#define D 256

#define C2    2.8853900817779268f   // 2/ln(2): exp(2x) = exp2(C2*x)
#define LOG2E 1.4426950408889634f

// 4-way division combine: q += sum_i v_i / p_i with ONE rcp.
__device__ __forceinline__ void qcomb4(float& q, const float4& v,
                                       float p0, float p1, float p2, float p3)
{
    const float n01 = fmaf(v.y, p0, v.x * p1);
    const float d01 = p0 * p1;
    const float n23 = fmaf(v.w, p2, v.z * p3);
    const float d23 = p2 * p3;
    const float num = fmaf(n23, d01, n01 * d23);
    const float den = d01 * d23;
    q = fmaf(num, __builtin_amdgcn_rcpf(den), q);
}

__device__ __forceinline__ void score4(float& q, const float4& v4,
                                       const float4& w, const float4& a)
{
    qcomb4(q, v4, fmaf(w.x, a.x, 1.0f), fmaf(w.y, a.y, 1.0f),
                  fmaf(w.z, a.z, 1.0f), fmaf(w.w, a.w, 1.0f));
}

// ---------------------------------------------------------------------------
// K1: projections + exp2. 384 blocks x 256 threads (round-3 skeleton).
// enc blocks (0..255): float4-d output layout ewt4[b][dd][e] = float4 over
//   d = 4dd..4dd+3 (round-1 layout; makes K2's score loads dwordx4).
// dec blocks (256..383): eu[b][t][d], unchanged.
// b-affine XCD swizzle on both paths (neutral-verified, kept for locality).
// ---------------------------------------------------------------------------
__global__ __launch_bounds__(256) void proj_kernel(
    const float* __restrict__ enc, const float* __restrict__ dec,
    const float* __restrict__ Wa,  const float* __restrict__ Ua,
    float* __restrict__ ewt, float* __restrict__ eu)
{
    __shared__ float a_lds[8 * 256];
    const int tid = threadIdx.x;
    const int blk = blockIdx.x;
    const bool is_enc = blk < 256;
    const float* __restrict__ A = is_enc ? enc : dec;
    const float* __restrict__ W = is_enc ? Wa  : Ua;

    int row0;
    if (is_enc) {
        const int xcd = blk & 7;
        const int b   = xcd >> 1;
        const int j   = ((xcd & 1) << 5) | (blk >> 3);     // 0..63
        row0 = b * 512 + j * 8;                            // flattened enc row
    } else {
        const int blk2 = blk - 256;                        // 0..127
        const int xcd  = blk2 & 7;
        const int b    = xcd >> 1;
        const int j    = ((xcd & 1) << 4) | (blk2 >> 3);   // 0..31
        row0 = b * 256 + j * 8;                            // flattened dec row
    }

    {
        const float4* src = (const float4*)(A + (size_t)row0 * 256);
        ((float4*)a_lds)[tid]       = src[tid];
        ((float4*)a_lds)[tid + 256] = src[tid + 256];
    }
    __syncthreads();

    float acc[8] = {0.f,0.f,0.f,0.f,0.f,0.f,0.f,0.f};

    #pragma unroll 4
    for (int k = 0; k < 256; k += 4) {
        const float w0 = W[(k + 0) * 256 + tid];
        const float w1 = W[(k + 1) * 256 + tid];
        const float w2 = W[(k + 2) * 256 + tid];
        const float w3 = W[(k + 3) * 256 + tid];
        #pragma unroll
        for (int r = 0; r < 8; r++) {
            const float4 a4 = *(const float4*)&a_lds[r * 256 + k];
            acc[r] = fmaf(a4.x, w0, acc[r]);
            acc[r] = fmaf(a4.y, w1, acc[r]);
            acc[r] = fmaf(a4.z, w2, acc[r]);
            acc[r] = fmaf(a4.w, w3, acc[r]);
        }
    }

    float f[8];
    #pragma unroll
    for (int r = 0; r < 8; r++)
        f[r] = __builtin_amdgcn_exp2f(acc[r] * C2);

    if (is_enc) {
        const int b  = row0 >> 9;
        const int e0 = row0 & 511;
        // ewt4[b][tid>>2][e0+r], component tid&3
        float* o = ewt + (((size_t)(b * 64 + (tid >> 2)) * 512 + e0) << 2)
                       + (tid & 3);
        #pragma unroll
        for (int r = 0; r < 8; r++)
            o[r * 4] = f[r];
    } else {
        #pragma unroll
        for (int r = 0; r < 8; r++)
            eu[(size_t)(row0 + r) * 256 + tid] = f[r];
    }
}

// ---------------------------------------------------------------------------
// K2: fused score + softmax + context. 256 blocks x 1024 threads, b-affine.
// Score (round-1 d-split, correctness-verified): e = tid&511 serves ALL 4
//   t's over a d-half (tp = tid>>9); 32 dwordx4 ewt loads per thread (was
//   256 dwords); halves combined via LDS. 2x fewer L2 bytes, 8x fewer VMEM
//   instructions; VALU identical.
// Softmax / context: unchanged from the 106 us build.
// ---------------------------------------------------------------------------
__global__ __launch_bounds__(1024) void attn_kernel(
    const float* __restrict__ enc, const float* __restrict__ ewt,
    const float* __restrict__ eu,  const float* __restrict__ Va,
    float* __restrict__ ctx, float* __restrict__ aw)
{
    __shared__ float eul[4 * 256];      // 4 Eu rows
    __shared__ float val[256];          // Va
    __shared__ float sc[4][TE];         // scores -> weights (8 KB)
    __shared__ float wred[2][4][4];     // softmax cross-wave combine
    __shared__ float part[4][4][256];   // scratch: score halves / ctx partials

    const int tid = threadIdx.x;
    const int blk = blockIdx.x;
    const int xcd = blk & 7;
    const int b   = xcd >> 1;                         // 2 XCDs per batch
    const int tq  = ((xcd & 1) << 5) | (blk >> 3);    // 0..63 t-quad
    const int t0  = tq * 4;
    const int bt0 = b * 256 + t0;

    float* const scratch = &part[0][0][0];            // 4096 floats

    if (tid < 256) val[tid] = Va[tid];
    eul[tid] = eu[(size_t)bt0 * 256 + tid];
    __syncthreads();

    // ---- scores: score'[t][e] = -2 * sum_d v_d / (1 + Ew*Eu) ------------
    {
        const int e  = tid & 511;
        const int tp = tid >> 9;           // d-half: d in [128*tp, 128*tp+128)
        const float4* __restrict__ ewb =
            (const float4*)ewt + (size_t)(b * 64 + tp * 32) * 512 + e;
        float q0 = 0.f, q1 = 0.f, q2 = 0.f, q3 = 0.f;

        #pragma unroll 2
        for (int it = 0; it < 16; ++it) {
            const float4 w0 = ewb[(it * 2 + 0) * 512];   // d-quad 2it
            const float4 w1 = ewb[(it * 2 + 1) * 512];   // d-quad 2it+1
            const int d0 = (tp * 32 + it * 2) * 4;
            {
                const float4 v4 = *(const float4*)&val[d0];
                score4(q0, v4, w0, *(const float4*)&eul[      d0]);
                score4(q1, v4, w0, *(const float4*)&eul[256 + d0]);
                score4(q2, v4, w0, *(const float4*)&eul[512 + d0]);
                score4(q3, v4, w0, *(const float4*)&eul[768 + d0]);
            }
            {
                const int d1 = d0 + 4;
                const float4 v4 = *(const float4*)&val[d1];
                score4(q0, v4, w1, *(const float4*)&eul[      d1]);
                score4(q1, v4, w1, *(const float4*)&eul[256 + d1]);
                score4(q2, v4, w1, *(const float4*)&eul[512 + d1]);
                score4(q3, v4, w1, *(const float4*)&eul[768 + d1]);
            }
        }

        if (tp) {
            scratch[       e] = q0;
            scratch[512  + e] = q1;
            scratch[1024 + e] = q2;
            scratch[1536 + e] = q3;
        }
        __syncthreads();
        if (!tp) {
            sc[0][e] = -2.0f * (q0 + scratch[       e]);
            sc[1][e] = -2.0f * (q1 + scratch[512  + e]);
            sc[2][e] = -2.0f * (q2 + scratch[1024 + e]);
            sc[3][e] = -2.0f * (q3 + scratch[1536 + e]);
        }
    }
    __syncthreads();

    // ---- softmax: wave wv -> (t = wv>>2, seg = wv&3) ---------------------
    {
        const int wv   = tid >> 6;
        const int lane = tid & 63;
        const int t    = wv >> 2;
        const int seg  = wv & 3;
        float* __restrict__ srow = &sc[t][seg * 128];

        const float x0 = srow[lane];
        const float x1 = srow[lane + 64];

        float m = fmaxf(x0, x1);
        #pragma unroll
        for (int s = 32; s > 0; s >>= 1) m = fmaxf(m, __shfl_xor(m, s, 64));
        if (lane == 0) wred[0][t][seg] = m;
        __syncthreads();
        const float4 mm = *(const float4*)&wred[0][t][0];
        const float M = fmaxf(fmaxf(mm.x, mm.y), fmaxf(mm.z, mm.w));

        const float g0 = __builtin_amdgcn_exp2f((x0 - M) * LOG2E);
        const float g1 = __builtin_amdgcn_exp2f((x1 - M) * LOG2E);

        float ssum = g0 + g1;
        #pragma unroll
        for (int s = 32; s > 0; s >>= 1) ssum += __shfl_xor(ssum, s, 64);
        if (lane == 0) wred[1][t][seg] = ssum;
        __syncthreads();
        const float4 sm = *(const float4*)&wred[1][t][0];
        const float inv = __builtin_amdgcn_rcpf((sm.x + sm.y) + (sm.z + sm.w));

        const float p0 = g0 * inv, p1 = g1 * inv;
        srow[lane]      = p0;
        srow[lane + 64] = p1;
        float* __restrict__ ao = aw + ((size_t)(bt0 + t)) * 512 + seg * 128;
        ao[lane]      = p0;
        ao[lane + 64] = p1;
    }
    __syncthreads();

    // ---- context: eg = tid>>8 (128 e's each), dl = tid&255 ---------------
    {
        const int eg = tid >> 8;
        const int dl = tid & 255;
        const float* __restrict__ eb =
            enc + ((size_t)b * 512 + eg * 128) * 256 + dl;
        const int e0 = eg * 128;

        float c0 = 0.f, c1 = 0.f, c2 = 0.f, c3 = 0.f;
        #pragma unroll 4
        for (int jj = 0; jj < 128; jj += 4) {
            const float4 w0 = *(const float4*)&sc[0][e0 + jj];
            const float4 w1 = *(const float4*)&sc[1][e0 + jj];
            const float4 w2 = *(const float4*)&sc[2][e0 + jj];
            const float4 w3 = *(const float4*)&sc[3][e0 + jj];
            const float r0 = eb[(jj + 0) * 256];
            const float r1 = eb[(jj + 1) * 256];
            const float r2 = eb[(jj + 2) * 256];
            const float r3 = eb[(jj + 3) * 256];
            c0 = fmaf(w0.x, r0, c0); c0 = fmaf(w0.y, r1, c0); c0 = fmaf(w0.z, r2, c0); c0 = fmaf(w0.w, r3, c0);
            c1 = fmaf(w1.x, r0, c1); c1 = fmaf(w1.y, r1, c1); c1 = fmaf(w1.z, r2, c1); c1 = fmaf(w1.w, r3, c1);
            c2 = fmaf(w2.x, r0, c2); c2 = fmaf(w2.y, r1, c2); c2 = fmaf(w2.z, r2, c2); c2 = fmaf(w2.w, r3, c2);
            c3 = fmaf(w3.x, r0, c3); c3 = fmaf(w3.y, r1, c3); c3 = fmaf(w3.z, r2, c3); c3 = fmaf(w3.w, r3, c3);
        }
        part[eg][0][dl] = c0;
        part[eg][1][dl] = c1;
        part[eg][2][dl] = c2;
        part[eg][3][dl] = c3;
    }
    __syncthreads();

    {
        const int t  = tid >> 8;       // 0..3
        const int dl = tid & 255;
        ctx[((size_t)(bt0 + t)) * 256 + dl] =
            (part[0][t][dl] + part[1][t][dl]) +
            (part[2][t][dl] + part[3][t][dl]);
    }
}

extern "C" void kernel_launch(void* const* d_in, const int* in_sizes, int n_in,
                              void* d_out, int out_size, void* d_ws, size_t ws_size,
                              hipStream_t stream) {
    const float* enc = (const float*)d_in[0];   // [4,512,256]
    const float* dec = (const float*)d_in[1];   // [4,256,256]
    const float* Wa  = (const float*)d_in[2];   // [256,256]
    const float* Ua  = (const float*)d_in[3];   // [256,256]
    const float* Va  = (const float*)d_in[4];   // [256,1]

    float* out = (float*)d_out;
    float* ctx = out;                           // [4,256,256]
    float* aw  = out + B * TD * D;              // [4,256,512]

    float* ewt = (float*)d_ws;                  // [4][64 dd][512 e] float4, 2 MB
    float* eu  = ewt + (size_t)B * D * TE;      // [4][256 t][256 d], 1 MB

    proj_kernel<<<dim3(384), dim3(256), 0, stream>>>(enc, dec, Wa, Ua, ewt, eu);
    attn_kernel<<<dim3(256), dim3(1024), 0, stream>>>(enc, ewt, eu, Va, ctx, aw);
}